// Round 8
// baseline (363.416 us; speedup 1.0000x reference)
//
#include <hip/hip_runtime.h>
#include <stdint.h>

#define DMODEL 1024
#define NHEADS 16
#define DK     64
#define BATCH  4
#define SEQ    2048
#define MROWS  (BATCH*SEQ)   // 8192

typedef __bf16 bf16x8 __attribute__((ext_vector_type(8)));
typedef float  f32x4  __attribute__((ext_vector_type(4)));

#if defined(__has_builtin)
#if __has_builtin(__builtin_amdgcn_exp2f)
#define EXP2F(x) __builtin_amdgcn_exp2f(x)
#endif
#endif
#ifndef EXP2F
#define EXP2F(x) exp2f(x)
#endif

__device__ __forceinline__ unsigned short f2bf(float f) {
    unsigned int u = __builtin_bit_cast(unsigned int, f);
    u += 0x7fffu + ((u >> 16) & 1u);   // round-to-nearest-even
    return (unsigned short)(u >> 16);
}

// pack two f32 -> two bf16 (round-to-nearest) in one v_perm
__device__ __forceinline__ unsigned int pack_bf16(float a, float b) {
    unsigned int ua = __builtin_bit_cast(unsigned int, a) + 0x8000u;
    unsigned int ub = __builtin_bit_cast(unsigned int, b) + 0x8000u;
    return __builtin_amdgcn_perm(ub, ua, 0x07060302u);  // lo16=a.hi16, hi16=b.hi16
}

// async global->LDS, 16 B per lane, LDS dest = uniform base + lane*16
#define GLDS(gp, lp) __builtin_amdgcn_global_load_lds( \
    (const __attribute__((address_space(1))) unsigned int*)(gp), \
    (__attribute__((address_space(3))) unsigned int*)(lp), 16, 0, 0)

// ------ fused prep: x + 4 weights fp32->bf16, and mask int32 -> float bias -----------
// one launch; 4 elems (16B read / 8B write) per thread, fully coalesced
#define XBLK (MROWS * DMODEL / 4 / 256)            // 8192
#define WBLK (4 * DMODEL * DMODEL / 4 / 256)       // 4096
#define MBLK (BATCH * SEQ / 4 / 256)               // 8
__global__ void prep_kernel(const float* __restrict__ x,
                            const float* __restrict__ w0, const float* __restrict__ w1,
                            const float* __restrict__ w2, const float* __restrict__ w3,
                            const int* __restrict__ mask,
                            unsigned short* __restrict__ xb,
                            unsigned short* __restrict__ d0, unsigned short* __restrict__ d1,
                            unsigned short* __restrict__ d2, unsigned short* __restrict__ d3,
                            float* __restrict__ mbf) {
    const int bx = blockIdx.x;
    if (bx >= XBLK + WBLK) {                              // 8 blocks: mask -> bias
        const int i = (bx - XBLK - WBLK) * 256 + threadIdx.x;
        const int4 mi = reinterpret_cast<const int4*>(mask)[i];
        float4 o;
        o.x = mi.x ? 0.f : -1e30f;
        o.y = mi.y ? 0.f : -1e30f;
        o.z = mi.z ? 0.f : -1e30f;
        o.w = mi.w ? 0.f : -1e30f;
        reinterpret_cast<float4*>(mbf)[i] = o;
        return;
    }
    const float* s; unsigned short* d; int i;
    if (bx < XBLK) {                                      // 8192 blocks: x
        s = x; d = xb; i = bx * 256 + threadIdx.x;
    } else {                                              // 4 x 1024 blocks: weights
        const int wb = bx - XBLK;
        const int wsel = wb >> 10;
        i = (wb & 1023) * 256 + threadIdx.x;
        switch (wsel) {
            case 0:  s = w0; d = d0; break;
            case 1:  s = w1; d = d1; break;
            case 2:  s = w2; d = d2; break;
            default: s = w3; d = d3; break;
        }
    }
    const float4 v = reinterpret_cast<const float4*>(s)[i];
    ushort4 o;
    o.x = f2bf(v.x); o.y = f2bf(v.y); o.z = f2bf(v.z); o.w = f2bf(v.w);
    reinterpret_cast<ushort4*>(d)[i] = o;
}

// ---------------- 128x128-tile GEMM, BK=64, LDS staged (r3 known-good) ----------------
// C[M,N] = A[M,1024] * W[N,1024]^T + bias
// launch_bounds(256,4): 4 blocks/CU (LDS 32 KB allows 5; VGPR est ~120 fits 128-cap).
// MODE 0: fused QKV. blockIdx.x: 0..23 -> which = x>>3 (0=Q,1=K,2=V), ntile = x&7
//         Q scaled by 0.125*log2(e); Q,K scatter -> [BH, L, 64];
//         V scatter -> blocked [BH, kblk, dv, 64]
// MODE 1: fp32 row-major out [M, 1024]
template<int MODE>
__global__ __launch_bounds__(256, 4) void gemm128(
        const unsigned short* __restrict__ A,
        const unsigned short* __restrict__ W0,
        const unsigned short* __restrict__ W1,
        const unsigned short* __restrict__ W2,
        const float* __restrict__ b0,
        const float* __restrict__ b1,
        const float* __restrict__ b2,
        void* __restrict__ o0, void* __restrict__ o1, void* __restrict__ o2) {
    __shared__ unsigned short As[128 * 64];   // 16 KB, rows of 64 bf16, chunk-swizzled
    __shared__ unsigned short Bs[128 * 64];   // 16 KB
    const int lane = threadIdx.x & 63;
    const int wave = threadIdx.x >> 6;
    const int quad = lane >> 4;
    const int r15  = lane & 15;
    const int wr = wave >> 1, wc = wave & 1;
    const int m0 = blockIdx.y * 128;

    int which, ncol0;
    const unsigned short* W;
    const float* bias;
    if (MODE == 0) {
        which = blockIdx.x >> 3;
        ncol0 = (blockIdx.x & 7) * 128;
        W    = which == 0 ? W0 : (which == 1 ? W1 : W2);
        bias = which == 0 ? b0 : (which == 1 ? b1 : b2);
    } else {
        which = 0; ncol0 = blockIdx.x * 128; W = W0; bias = b0;
    }

    // staging: lane covers (row = seg*8 + lane/8, chunk = lane&7),
    // global chunk swizzled by row&7 so LDS stays DMA-contiguous yet reads conflict-free
    const int srow = lane >> 3;
    const int scg  = (lane & 7) ^ srow;
    const unsigned short* Ag[4];
    const unsigned short* Wg[4];
    #pragma unroll
    for (int j = 0; j < 4; ++j) {
        const int row = (wave * 4 + j) * 8 + srow;
        Ag[j] = A + (m0 + row) * DMODEL + scg * 8;
        Wg[j] = W + (ncol0 + row) * DMODEL + scg * 8;
    }

    f32x4 acc[4][4] = {};
    for (int kk = 0; kk < DMODEL; kk += 64) {
        __syncthreads();
        #pragma unroll
        for (int j = 0; j < 4; ++j) {
            GLDS(Ag[j] + kk, &As[(wave * 4 + j) * 512]);
            GLDS(Wg[j] + kk, &Bs[(wave * 4 + j) * 512]);
        }
        __syncthreads();
        #pragma unroll
        for (int u = 0; u < 2; ++u) {
            bf16x8 af[4], bfx[4];
            const int cs = ((u * 4 + quad) ^ (r15 & 7)) * 8;
            #pragma unroll
            for (int t = 0; t < 4; ++t) {
                af[t]  = *(const bf16x8*)&As[(wr * 64 + t * 16 + r15) * 64 + cs];
                bfx[t] = *(const bf16x8*)&Bs[(wc * 64 + t * 16 + r15) * 64 + cs];
            }
            #pragma unroll
            for (int mt = 0; mt < 4; ++mt)
                #pragma unroll
                for (int nt = 0; nt < 4; ++nt)
                    acc[mt][nt] = __builtin_amdgcn_mfma_f32_16x16x32_bf16(
                        af[mt], bfx[nt], acc[mt][nt], 0, 0, 0);
        }
    }

    // epilogue
    #pragma unroll
    for (int mt = 0; mt < 4; ++mt) {
        #pragma unroll
        for (int nt = 0; nt < 4; ++nt) {
            #pragma unroll
            for (int r = 0; r < 4; ++r) {
                const int row = m0 + wr * 64 + mt * 16 + quad * 4 + r;  // C row = quad*4+reg
                const int col = ncol0 + wc * 64 + nt * 16 + r15;        // C col = lane&15
                float v = acc[mt][nt][r] + bias[col];
                if (MODE == 1) {
                    ((float*)o0)[(size_t)row * DMODEL + col] = v;
                } else {
                    if (which == 0) v *= 0.18033688011112042f;  // 0.125*log2(e)
                    const int b = row >> 11, l = row & (SEQ - 1);
                    const int h = col >> 6,  d = col & (DK - 1);
                    const int bh = b * NHEADS + h;
                    unsigned short* ow = (unsigned short*)(which == 0 ? o0 : (which == 1 ? o1 : o2));
                    size_t idx;
                    if (which < 2) idx = ((size_t)bh * SEQ + l) * DK + d;
                    else           idx = (size_t)bh * (SEQ * DK) + (l >> 6) * (DK * 64) + d * 64 + (l & 63);
                    ow[idx] = f2bf(v);
                }
            }
        }
    }
}

// ---------------- Flash attention: K double-buffered, V single, 40 KB LDS (r6 best) ------
// LDS = 16 (K dbuf) + 8 (V) + 16 (P) = 40 KB exactly -> 4 blocks/CU (grid is 4 blocks/CU!)
// Per tile: issue K[t+1]; QK^T+softmax hides V[t] and K[t+1]; barrier; PV; barrier;
// issue V[t+1] (hidden under next tile's QK^T).
__global__ __launch_bounds__(256, 4) void flash_attn(
        const unsigned short* __restrict__ Q,
        const unsigned short* __restrict__ Km,
        const unsigned short* __restrict__ Vm,
        const float* __restrict__ mbf,
        unsigned short* __restrict__ Oa) {
    __shared__ unsigned short Ks[2][64 * 64];     // 16 KB  [key][dk] swizzled, dbuf
    __shared__ unsigned short Vs[64 * 64];        // 8 KB   [dv][key] swizzled
    __shared__ unsigned short Pl[4][2][16 * 64];  // 16 KB  [wave][qf][q][key] swizzled
    const int lane = threadIdx.x & 63;
    const int wave = threadIdx.x >> 6;
    const int quad = lane >> 4;
    const int r15  = lane & 15;

    // XCD-aware remap: each XCD walks one head's 16 q-tiles before moving on
    const int id   = (blockIdx.y << 4) | blockIdx.x;   // gridDim.x == 16
    const int xcd  = id & 7;
    const int slot = id >> 3;                          // 0..127
    const int bh   = xcd + ((slot >> 4) << 3);         // 0..63
    const int qt   = slot & 15;
    const int b = bh >> 4, h = bh & (NHEADS - 1);
    const int q0 = qt * 128 + wave * 32;

    const unsigned short* Qb = Q  + (size_t)bh * SEQ * DK;
    const unsigned short* Kb = Km + (size_t)bh * SEQ * DK;
    const unsigned short* Vb = Vm + (size_t)bh * SEQ * DK;
    const float* mb = mbf + b * SEQ;

    const int srow = lane >> 3;
    const int soff = ((lane >> 3) * 64) + (((lane & 7) ^ srow) * 8);

    // Q fragments (B operand of S^T MFMA): 2 q-frags x 2 k-halves
    bf16x8 bq[2][2];
    #pragma unroll
    for (int qf = 0; qf < 2; ++qf)
        #pragma unroll
        for (int u = 0; u < 2; ++u)
            bq[qf][u] = *(const bf16x8*)(Qb + (q0 + qf * 16 + r15) * DK + u * 32 + quad * 8);

    float l_part[2] = {0.f, 0.f};
    f32x4 oacc[2][4] = {};

    // prologue: stage K[0] into Ks[0] and V[0] into Vs
    #pragma unroll
    for (int j = 0; j < 2; ++j) {
        const int wseg = wave * 2 + j;
        GLDS(Kb + wseg * 512 + soff, &Ks[0][wseg * 512]);
        GLDS(Vb + wseg * 512 + soff, &Vs[wseg * 512]);
    }
    __syncthreads();   // K[0], V[0] resident

    #define NT (SEQ / 64)
    for (int t = 0; t < NT; ++t) {
        const int kb = t * 64;
        const int cur = t & 1;

        // mask-bias loads for this tile, issued BEFORE the prefetch so their
        // waitcnt doesn't force the prefetch to drain
        float4 m4v[4];
        #pragma unroll
        for (int tt = 0; tt < 4; ++tt)
            m4v[tt] = *(const float4*)(mb + kb + tt * 16 + quad * 4);

        // prefetch K[t+1] into the other K buffer; lands under softmax below
        if (t + 1 < NT) {
            const unsigned short* Kg = Kb + (kb + 64) * 64;
            #pragma unroll
            for (int j = 0; j < 2; ++j) {
                const int wseg = wave * 2 + j;
                GLDS(Kg + wseg * 512 + soff, &Ks[cur ^ 1][wseg * 512]);
            }
        }

        char* const Pb = (char*)&Pl[wave][0][0];
        #pragma unroll
        for (int tt = 0; tt < 4; ++tt) {
            const bf16x8 ak0 = *(const bf16x8*)&Ks[cur][(tt * 16 + r15) * 64 + ((quad ^ (r15 & 7)) * 8)];
            const bf16x8 ak1 = *(const bf16x8*)&Ks[cur][(tt * 16 + r15) * 64 + (((4 + quad) ^ (r15 & 7)) * 8)];
            const float4 m4 = m4v[tt];
            #pragma unroll
            for (int qf = 0; qf < 2; ++qf) {
                f32x4 z = {};
                z = __builtin_amdgcn_mfma_f32_16x16x32_bf16(ak0, bq[qf][0], z, 0, 0, 0);
                z = __builtin_amdgcn_mfma_f32_16x16x32_bf16(ak1, bq[qf][1], z, 0, 0, 0);
                // z = S^T (already in log2 domain): lane holds (key=tt*16+quad*4+r, query=r15)
                const float p0 = EXP2F(z[0] + m4.x);
                const float p1 = EXP2F(z[1] + m4.y);
                const float p2 = EXP2F(z[2] + m4.z);
                const float p3 = EXP2F(z[3] + m4.w);
                l_part[qf] += (p0 + p1) + (p2 + p3);
                uint2 pw;
                pw.x = pack_bf16(p0, p1);
                pw.y = pack_bf16(p2, p3);
                const int c2 = (tt * 2 + (quad >> 1)) ^ (r15 & 7);
                *(uint2*)(Pb + qf * 2048 + r15 * 128 + c2 * 16 + (quad & 1) * 8) = pw;
            }
        }

        // BARRIER_A: drains own vmcnt (V[t] issued one tile ago: landed;
        // K[t+1] issued ~1200cy ago: landed) and makes all waves' V[t] visible
        __syncthreads();

        __builtin_amdgcn_s_setprio(1);
        #pragma unroll
        for (int u = 0; u < 2; ++u) {
            const int cs = ((u * 4 + quad) ^ (r15 & 7)) * 8;
            bf16x8 vf[4];
            #pragma unroll
            for (int nt = 0; nt < 4; ++nt)
                vf[nt] = *(const bf16x8*)&Vs[(nt * 16 + r15) * 64 + cs];
            #pragma unroll
            for (int qf = 0; qf < 2; ++qf) {
                const bf16x8 ap = *(const bf16x8*)(Pb + qf * 2048 + r15 * 128 + cs * 2);
                #pragma unroll
                for (int nt = 0; nt < 4; ++nt)
                    oacc[qf][nt] = __builtin_amdgcn_mfma_f32_16x16x32_bf16(
                        ap, vf[nt], oacc[qf][nt], 0, 0, 0);
            }
        }
        __builtin_amdgcn_s_setprio(0);

        // BARRIER_B: all waves done reading Vs -> safe to overwrite
        __syncthreads();

        // issue V[t+1]; hidden under next tile's QK^T+softmax, drained at next BARRIER_A
        if (t + 1 < NT) {
            const unsigned short* Vg = Vb + (kb + 64) * 64;
            #pragma unroll
            for (int j = 0; j < 2; ++j) {
                const int wseg = wave * 2 + j;
                GLDS(Vg + wseg * 512 + soff, &Vs[wseg * 512]);
            }
        }
    }
    #undef NT

    #pragma unroll
    for (int qf = 0; qf < 2; ++qf) {
        float l = l_part[qf];
        l += __shfl_xor(l, 16);
        l += __shfl_xor(l, 32);      // now: l for query r15 (within fragment qf)
        float lq[4];
        #pragma unroll
        for (int r = 0; r < 4; ++r) lq[r] = __shfl(l, quad * 4 + r, 64);
        #pragma unroll
        for (int nt = 0; nt < 4; ++nt) {
            #pragma unroll
            for (int r = 0; r < 4; ++r) {
                const int row = q0 + qf * 16 + quad * 4 + r;
                const int col = h * DK + nt * 16 + r15;
                Oa[((size_t)b * SEQ + row) * DMODEL + col] = f2bf(oacc[qf][nt][r] / lq[r]);
            }
        }
    }
}

extern "C" void kernel_launch(void* const* d_in, const int* in_sizes, int n_in,
                              void* d_out, int out_size, void* d_ws, size_t ws_size,
                              hipStream_t stream) {
    (void)in_sizes; (void)n_in; (void)out_size; (void)ws_size;
    const float* x  = (const float*)d_in[0];
    const int* mask = (const int*)d_in[1];
    const float* Wq = (const float*)d_in[2];
    const float* bq = (const float*)d_in[3];
    const float* Wk = (const float*)d_in[4];
    const float* bk = (const float*)d_in[5];
    const float* Wv = (const float*)d_in[6];
    const float* bv = (const float*)d_in[7];
    const float* Wo = (const float*)d_in[8];
    const float* bo = (const float*)d_in[9];
    float* out = (float*)d_out;

    char* ws = (char*)d_ws;
    unsigned short* xb  = (unsigned short*)(ws);                                   // 8192x1024 bf16
    unsigned short* wqb = (unsigned short*)(ws + 16777216);                        // 1024x1024 bf16
    unsigned short* wkb = (unsigned short*)(ws + 16777216 + 1 * 2097152);
    unsigned short* wvb = (unsigned short*)(ws + 16777216 + 2 * 2097152);
    unsigned short* wob = (unsigned short*)(ws + 16777216 + 3 * 2097152);
    unsigned short* qb  = (unsigned short*)(ws + 16777216 + 4 * 2097152);          // [BH,L,64]
    unsigned short* kb  = qb  + (size_t)MROWS * DMODEL;                            // [BH,L,64]
    unsigned short* vtb = kb  + (size_t)MROWS * DMODEL;                            // blocked V
    unsigned short* ab  = vtb + (size_t)MROWS * DMODEL;                            // [B,L,DMODEL]
    float*          mbf = (float*)(ab + (size_t)MROWS * DMODEL);                   // [B,L]

    // 4 launches total: prep (x/W cvt + mask bias), QKV gemm, flash, O-proj gemm
    prep_kernel<<<dim3(XBLK + WBLK + MBLK), 256, 0, stream>>>(
        x, Wq, Wk, Wv, Wo, mask, xb, wqb, wkb, wvb, wob, mbf);

    gemm128<0><<<dim3(24, MROWS / 128), 256, 0, stream>>>(
        xb, wqb, wkb, wvb, bq, bk, bv, qb, kb, vtb);

    flash_attn<<<dim3(16, BATCH * NHEADS), 256, 0, stream>>>(qb, kb, vtb, mbf, ab);

    gemm128<1><<<dim3(8, MROWS / 128), 256, 0, stream>>>(
        ab, wob, nullptr, nullptr, bo, nullptr, nullptr, out, nullptr, nullptr);
}

// Round 10
// 295.390 us; speedup vs baseline: 1.2303x; 1.2303x over previous
//
#include <hip/hip_runtime.h>
#include <stdint.h>

#define DMODEL 1024
#define NHEADS 16
#define DK     64
#define BATCH  4
#define SEQ    2048
#define MROWS  (BATCH*SEQ)   // 8192

typedef __bf16 bf16x8 __attribute__((ext_vector_type(8)));
typedef float  f32x4  __attribute__((ext_vector_type(4)));

#if defined(__has_builtin)
#if __has_builtin(__builtin_amdgcn_exp2f)
#define EXP2F(x) __builtin_amdgcn_exp2f(x)
#endif
#endif
#ifndef EXP2F
#define EXP2F(x) exp2f(x)
#endif

__device__ __forceinline__ unsigned short f2bf(float f) {
    unsigned int u = __builtin_bit_cast(unsigned int, f);
    u += 0x7fffu + ((u >> 16) & 1u);   // round-to-nearest-even
    return (unsigned short)(u >> 16);
}

// pack two f32 -> two bf16 (round-to-nearest) in one v_perm
__device__ __forceinline__ unsigned int pack_bf16(float a, float b) {
    unsigned int ua = __builtin_bit_cast(unsigned int, a) + 0x8000u;
    unsigned int ub = __builtin_bit_cast(unsigned int, b) + 0x8000u;
    return __builtin_amdgcn_perm(ub, ua, 0x07060302u);  // lo16=a.hi16, hi16=b.hi16
}

// async global->LDS, 16 B per lane, LDS dest = uniform base + lane*16
#define GLDS(gp, lp) __builtin_amdgcn_global_load_lds( \
    (const __attribute__((address_space(1))) unsigned int*)(gp), \
    (__attribute__((address_space(3))) unsigned int*)(lp), 16, 0, 0)

// ------ fused prep: x + 4 weights fp32->bf16, and mask int32 -> float bias -----------
// one launch; 4 elems (16B read / 8B write) per thread, fully coalesced
#define XBLK (MROWS * DMODEL / 4 / 256)            // 8192
#define WBLK (4 * DMODEL * DMODEL / 4 / 256)       // 4096
#define MBLK (BATCH * SEQ / 4 / 256)               // 8
__global__ void prep_kernel(const float* __restrict__ x,
                            const float* __restrict__ w0, const float* __restrict__ w1,
                            const float* __restrict__ w2, const float* __restrict__ w3,
                            const int* __restrict__ mask,
                            unsigned short* __restrict__ xb,
                            unsigned short* __restrict__ d0, unsigned short* __restrict__ d1,
                            unsigned short* __restrict__ d2, unsigned short* __restrict__ d3,
                            float* __restrict__ mbf) {
    const int bx = blockIdx.x;
    if (bx >= XBLK + WBLK) {                              // 8 blocks: mask -> bias
        const int i = (bx - XBLK - WBLK) * 256 + threadIdx.x;
        const int4 mi = reinterpret_cast<const int4*>(mask)[i];
        float4 o;
        o.x = mi.x ? 0.f : -1e30f;
        o.y = mi.y ? 0.f : -1e30f;
        o.z = mi.z ? 0.f : -1e30f;
        o.w = mi.w ? 0.f : -1e30f;
        reinterpret_cast<float4*>(mbf)[i] = o;
        return;
    }
    const float* s; unsigned short* d; int i;
    if (bx < XBLK) {                                      // 8192 blocks: x
        s = x; d = xb; i = bx * 256 + threadIdx.x;
    } else {                                              // 4 x 1024 blocks: weights
        const int wb = bx - XBLK;
        const int wsel = wb >> 10;
        i = (wb & 1023) * 256 + threadIdx.x;
        switch (wsel) {
            case 0:  s = w0; d = d0; break;
            case 1:  s = w1; d = d1; break;
            case 2:  s = w2; d = d2; break;
            default: s = w3; d = d3; break;
        }
    }
    const float4 v = reinterpret_cast<const float4*>(s)[i];
    ushort4 o;
    o.x = f2bf(v.x); o.y = f2bf(v.y); o.z = f2bf(v.z); o.w = f2bf(v.w);
    reinterpret_cast<ushort4*>(d)[i] = o;
}

// ---------------- 128x128-tile GEMM, BK=64, LDS staged (r3 known-good) ----------------
// C[M,N] = A[M,1024] * W[N,1024]^T + bias
// launch_bounds(256,3): 3 blocks/CU. DO NOT raise to 4 — r8 measured: the allocator
// squeezes to 64 VGPR and spills acc to scratch (FETCH 137MB/WRITE 248MB, 2.2x slower).
// MODE 0: fused QKV. blockIdx.x: 0..23 -> which = x>>3 (0=Q,1=K,2=V), ntile = x&7
//         Q scaled by 0.125*log2(e); Q,K scatter -> [BH, L, 64];
//         V scatter -> blocked [BH, kblk, dv, 64]
// MODE 1: fp32 row-major out [M, 1024]
template<int MODE>
__global__ __launch_bounds__(256, 3) void gemm128(
        const unsigned short* __restrict__ A,
        const unsigned short* __restrict__ W0,
        const unsigned short* __restrict__ W1,
        const unsigned short* __restrict__ W2,
        const float* __restrict__ b0,
        const float* __restrict__ b1,
        const float* __restrict__ b2,
        void* __restrict__ o0, void* __restrict__ o1, void* __restrict__ o2) {
    __shared__ unsigned short As[128 * 64];   // 16 KB, rows of 64 bf16, chunk-swizzled
    __shared__ unsigned short Bs[128 * 64];   // 16 KB
    const int lane = threadIdx.x & 63;
    const int wave = threadIdx.x >> 6;
    const int quad = lane >> 4;
    const int r15  = lane & 15;
    const int wr = wave >> 1, wc = wave & 1;
    const int m0 = blockIdx.y * 128;

    int which, ncol0;
    const unsigned short* W;
    const float* bias;
    if (MODE == 0) {
        which = blockIdx.x >> 3;
        ncol0 = (blockIdx.x & 7) * 128;
        W    = which == 0 ? W0 : (which == 1 ? W1 : W2);
        bias = which == 0 ? b0 : (which == 1 ? b1 : b2);
    } else {
        which = 0; ncol0 = blockIdx.x * 128; W = W0; bias = b0;
    }

    // staging: lane covers (row = seg*8 + lane/8, chunk = lane&7),
    // global chunk swizzled by row&7 so LDS stays DMA-contiguous yet reads conflict-free
    const int srow = lane >> 3;
    const int scg  = (lane & 7) ^ srow;
    const unsigned short* Ag[4];
    const unsigned short* Wg[4];
    #pragma unroll
    for (int j = 0; j < 4; ++j) {
        const int row = (wave * 4 + j) * 8 + srow;
        Ag[j] = A + (m0 + row) * DMODEL + scg * 8;
        Wg[j] = W + (ncol0 + row) * DMODEL + scg * 8;
    }

    f32x4 acc[4][4] = {};
    for (int kk = 0; kk < DMODEL; kk += 64) {
        __syncthreads();
        #pragma unroll
        for (int j = 0; j < 4; ++j) {
            GLDS(Ag[j] + kk, &As[(wave * 4 + j) * 512]);
            GLDS(Wg[j] + kk, &Bs[(wave * 4 + j) * 512]);
        }
        __syncthreads();
        #pragma unroll
        for (int u = 0; u < 2; ++u) {
            bf16x8 af[4], bfx[4];
            const int cs = ((u * 4 + quad) ^ (r15 & 7)) * 8;
            #pragma unroll
            for (int t = 0; t < 4; ++t) {
                af[t]  = *(const bf16x8*)&As[(wr * 64 + t * 16 + r15) * 64 + cs];
                bfx[t] = *(const bf16x8*)&Bs[(wc * 64 + t * 16 + r15) * 64 + cs];
            }
            #pragma unroll
            for (int mt = 0; mt < 4; ++mt)
                #pragma unroll
                for (int nt = 0; nt < 4; ++nt)
                    acc[mt][nt] = __builtin_amdgcn_mfma_f32_16x16x32_bf16(
                        af[mt], bfx[nt], acc[mt][nt], 0, 0, 0);
        }
    }

    // epilogue
    #pragma unroll
    for (int mt = 0; mt < 4; ++mt) {
        #pragma unroll
        for (int nt = 0; nt < 4; ++nt) {
            #pragma unroll
            for (int r = 0; r < 4; ++r) {
                const int row = m0 + wr * 64 + mt * 16 + quad * 4 + r;  // C row = quad*4+reg
                const int col = ncol0 + wc * 64 + nt * 16 + r15;        // C col = lane&15
                float v = acc[mt][nt][r] + bias[col];
                if (MODE == 1) {
                    ((float*)o0)[(size_t)row * DMODEL + col] = v;
                } else {
                    if (which == 0) v *= 0.18033688011112042f;  // 0.125*log2(e)
                    const int b = row >> 11, l = row & (SEQ - 1);
                    const int h = col >> 6,  d = col & (DK - 1);
                    const int bh = b * NHEADS + h;
                    unsigned short* ow = (unsigned short*)(which == 0 ? o0 : (which == 1 ? o1 : o2));
                    size_t idx;
                    if (which < 2) idx = ((size_t)bh * SEQ + l) * DK + d;
                    else           idx = (size_t)bh * (SEQ * DK) + (l >> 6) * (DK * 64) + d * 64 + (l & 63);
                    ow[idx] = f2bf(v);
                }
            }
        }
    }
}

// ---------------- Flash attention: K double-buffered, V single, 40 KB LDS (r6 best) ------
// LDS = 16 (K dbuf) + 8 (V) + 16 (P) = 40 KB exactly -> 4 blocks/CU (grid is 4 blocks/CU!)
// Per tile: issue K[t+1]; QK^T+softmax hides V[t] and K[t+1]; barrier; PV; barrier;
// issue V[t+1] (hidden under next tile's QK^T).
__global__ __launch_bounds__(256, 4) void flash_attn(
        const unsigned short* __restrict__ Q,
        const unsigned short* __restrict__ Km,
        const unsigned short* __restrict__ Vm,
        const float* __restrict__ mbf,
        unsigned short* __restrict__ Oa) {
    __shared__ unsigned short Ks[2][64 * 64];     // 16 KB  [key][dk] swizzled, dbuf
    __shared__ unsigned short Vs[64 * 64];        // 8 KB   [dv][key] swizzled
    __shared__ unsigned short Pl[4][2][16 * 64];  // 16 KB  [wave][qf][q][key] swizzled
    const int lane = threadIdx.x & 63;
    const int wave = threadIdx.x >> 6;
    const int quad = lane >> 4;
    const int r15  = lane & 15;

    // XCD-aware remap: each XCD walks one head's 16 q-tiles before moving on
    const int id   = (blockIdx.y << 4) | blockIdx.x;   // gridDim.x == 16
    const int xcd  = id & 7;
    const int slot = id >> 3;                          // 0..127
    const int bh   = xcd + ((slot >> 4) << 3);         // 0..63
    const int qt   = slot & 15;
    const int b = bh >> 4, h = bh & (NHEADS - 1);
    const int q0 = qt * 128 + wave * 32;

    const unsigned short* Qb = Q  + (size_t)bh * SEQ * DK;
    const unsigned short* Kb = Km + (size_t)bh * SEQ * DK;
    const unsigned short* Vb = Vm + (size_t)bh * SEQ * DK;
    const float* mb = mbf + b * SEQ;

    const int srow = lane >> 3;
    const int soff = ((lane >> 3) * 64) + (((lane & 7) ^ srow) * 8);

    // Q fragments (B operand of S^T MFMA): 2 q-frags x 2 k-halves
    bf16x8 bq[2][2];
    #pragma unroll
    for (int qf = 0; qf < 2; ++qf)
        #pragma unroll
        for (int u = 0; u < 2; ++u)
            bq[qf][u] = *(const bf16x8*)(Qb + (q0 + qf * 16 + r15) * DK + u * 32 + quad * 8);

    float l_part[2] = {0.f, 0.f};
    f32x4 oacc[2][4] = {};

    // prologue: stage K[0] into Ks[0] and V[0] into Vs
    #pragma unroll
    for (int j = 0; j < 2; ++j) {
        const int wseg = wave * 2 + j;
        GLDS(Kb + wseg * 512 + soff, &Ks[0][wseg * 512]);
        GLDS(Vb + wseg * 512 + soff, &Vs[wseg * 512]);
    }
    __syncthreads();   // K[0], V[0] resident

    #define NT (SEQ / 64)
    for (int t = 0; t < NT; ++t) {
        const int kb = t * 64;
        const int cur = t & 1;

        // mask-bias loads for this tile, issued BEFORE the prefetch so their
        // waitcnt doesn't force the prefetch to drain
        float4 m4v[4];
        #pragma unroll
        for (int tt = 0; tt < 4; ++tt)
            m4v[tt] = *(const float4*)(mb + kb + tt * 16 + quad * 4);

        // prefetch K[t+1] into the other K buffer; lands under softmax below
        if (t + 1 < NT) {
            const unsigned short* Kg = Kb + (kb + 64) * 64;
            #pragma unroll
            for (int j = 0; j < 2; ++j) {
                const int wseg = wave * 2 + j;
                GLDS(Kg + wseg * 512 + soff, &Ks[cur ^ 1][wseg * 512]);
            }
        }

        char* const Pb = (char*)&Pl[wave][0][0];
        #pragma unroll
        for (int tt = 0; tt < 4; ++tt) {
            const bf16x8 ak0 = *(const bf16x8*)&Ks[cur][(tt * 16 + r15) * 64 + ((quad ^ (r15 & 7)) * 8)];
            const bf16x8 ak1 = *(const bf16x8*)&Ks[cur][(tt * 16 + r15) * 64 + (((4 + quad) ^ (r15 & 7)) * 8)];
            const float4 m4 = m4v[tt];
            #pragma unroll
            for (int qf = 0; qf < 2; ++qf) {
                f32x4 z = {};
                z = __builtin_amdgcn_mfma_f32_16x16x32_bf16(ak0, bq[qf][0], z, 0, 0, 0);
                z = __builtin_amdgcn_mfma_f32_16x16x32_bf16(ak1, bq[qf][1], z, 0, 0, 0);
                // z = S^T (already in log2 domain): lane holds (key=tt*16+quad*4+r, query=r15)
                const float p0 = EXP2F(z[0] + m4.x);
                const float p1 = EXP2F(z[1] + m4.y);
                const float p2 = EXP2F(z[2] + m4.z);
                const float p3 = EXP2F(z[3] + m4.w);
                l_part[qf] += (p0 + p1) + (p2 + p3);
                uint2 pw;
                pw.x = pack_bf16(p0, p1);
                pw.y = pack_bf16(p2, p3);
                const int c2 = (tt * 2 + (quad >> 1)) ^ (r15 & 7);
                *(uint2*)(Pb + qf * 2048 + r15 * 128 + c2 * 16 + (quad & 1) * 8) = pw;
            }
        }

        // BARRIER_A: drains own vmcnt (V[t] issued one tile ago: landed;
        // K[t+1] issued ~1200cy ago: landed) and makes all waves' V[t] visible
        __syncthreads();

        __builtin_amdgcn_s_setprio(1);
        #pragma unroll
        for (int u = 0; u < 2; ++u) {
            const int cs = ((u * 4 + quad) ^ (r15 & 7)) * 8;
            bf16x8 vf[4];
            #pragma unroll
            for (int nt = 0; nt < 4; ++nt)
                vf[nt] = *(const bf16x8*)&Vs[(nt * 16 + r15) * 64 + cs];
            #pragma unroll
            for (int qf = 0; qf < 2; ++qf) {
                const bf16x8 ap = *(const bf16x8*)(Pb + qf * 2048 + r15 * 128 + cs * 2);
                #pragma unroll
                for (int nt = 0; nt < 4; ++nt)
                    oacc[qf][nt] = __builtin_amdgcn_mfma_f32_16x16x32_bf16(
                        ap, vf[nt], oacc[qf][nt], 0, 0, 0);
            }
        }
        __builtin_amdgcn_s_setprio(0);

        // BARRIER_B: all waves done reading Vs -> safe to overwrite
        __syncthreads();

        // issue V[t+1]; hidden under next tile's QK^T+softmax, drained at next BARRIER_A
        if (t + 1 < NT) {
            const unsigned short* Vg = Vb + (kb + 64) * 64;
            #pragma unroll
            for (int j = 0; j < 2; ++j) {
                const int wseg = wave * 2 + j;
                GLDS(Vg + wseg * 512 + soff, &Vs[wseg * 512]);
            }
        }
    }
    #undef NT

    #pragma unroll
    for (int qf = 0; qf < 2; ++qf) {
        float l = l_part[qf];
        l += __shfl_xor(l, 16);
        l += __shfl_xor(l, 32);      // now: l for query r15 (within fragment qf)
        float lq[4];
        #pragma unroll
        for (int r = 0; r < 4; ++r) lq[r] = __shfl(l, quad * 4 + r, 64);
        #pragma unroll
        for (int nt = 0; nt < 4; ++nt) {
            #pragma unroll
            for (int r = 0; r < 4; ++r) {
                const int row = q0 + qf * 16 + quad * 4 + r;
                const int col = h * DK + nt * 16 + r15;
                Oa[((size_t)b * SEQ + row) * DMODEL + col] = f2bf(oacc[qf][nt][r] / lq[r]);
            }
        }
    }
}

extern "C" void kernel_launch(void* const* d_in, const int* in_sizes, int n_in,
                              void* d_out, int out_size, void* d_ws, size_t ws_size,
                              hipStream_t stream) {
    (void)in_sizes; (void)n_in; (void)out_size; (void)ws_size;
    const float* x  = (const float*)d_in[0];
    const int* mask = (const int*)d_in[1];
    const float* Wq = (const float*)d_in[2];
    const float* bq = (const float*)d_in[3];
    const float* Wk = (const float*)d_in[4];
    const float* bk = (const float*)d_in[5];
    const float* Wv = (const float*)d_in[6];
    const float* bv = (const float*)d_in[7];
    const float* Wo = (const float*)d_in[8];
    const float* bo = (const float*)d_in[9];
    float* out = (float*)d_out;

    char* ws = (char*)d_ws;
    unsigned short* xb  = (unsigned short*)(ws);                                   // 8192x1024 bf16
    unsigned short* wqb = (unsigned short*)(ws + 16777216);                        // 1024x1024 bf16
    unsigned short* wkb = (unsigned short*)(ws + 16777216 + 1 * 2097152);
    unsigned short* wvb = (unsigned short*)(ws + 16777216 + 2 * 2097152);
    unsigned short* wob = (unsigned short*)(ws + 16777216 + 3 * 2097152);
    unsigned short* qb  = (unsigned short*)(ws + 16777216 + 4 * 2097152);          // [BH,L,64]
    unsigned short* kb  = qb  + (size_t)MROWS * DMODEL;                            // [BH,L,64]
    unsigned short* vtb = kb  + (size_t)MROWS * DMODEL;                            // blocked V
    unsigned short* ab  = vtb + (size_t)MROWS * DMODEL;                            // [B,L,DMODEL]
    float*          mbf = (float*)(ab + (size_t)MROWS * DMODEL);                   // [B,L]

    // 4 launches total: prep (x/W cvt + mask bias), QKV gemm, flash, O-proj gemm
    prep_kernel<<<dim3(XBLK + WBLK + MBLK), 256, 0, stream>>>(
        x, Wq, Wk, Wv, Wo, mask, xb, wqb, wkb, wvb, wob, mbf);

    gemm128<0><<<dim3(24, MROWS / 128), 256, 0, stream>>>(
        xb, wqb, wkb, wvb, bq, bk, bv, qb, kb, vtb);

    flash_attn<<<dim3(16, BATCH * NHEADS), 256, 0, stream>>>(qb, kb, vtb, mbf, ab);

    gemm128<1><<<dim3(8, MROWS / 128), 256, 0, stream>>>(
        ab, wob, nullptr, nullptr, bo, nullptr, nullptr, out, nullptr, nullptr);
}